// Round 6
// baseline (147.688 us; speedup 1.0000x reference)
//
#include <hip/hip_runtime.h>

#define N_PTS 20000
#define NCLS 20
#define KNN 16
#define GRID 12
#define NCELLS (GRID * GRID * GRID)
#define HCELL (1.0f / (float)GRID)
#define CAND_CAP 512       // 3^3 staged block: E~313 interior, +6 sigma < 512
#define KEY_CAP 128        // filtered keys per point (E~26, taumax E~49)
#define R_TARGET 0.0680f   // radius giving E[cnt]~26 in the interior

__device__ __forceinline__ int cell1d(float v) {
    int c = (int)(v * (float)GRID);
    return min(max(c, 0), GRID - 1);
}

// ---------------------------------------------------------------------------
// Count (grid-wide atomics) + fused scan: last block performs the 1728-cell
// exclusive scan (agent-scope loads; done-counter handshake).
// ---------------------------------------------------------------------------
__global__ __launch_bounds__(256) void count_scan_kernel(const float* __restrict__ coords,
                                                         int* __restrict__ cellCount,
                                                         int* __restrict__ doneCtr,
                                                         int* __restrict__ cellStart,
                                                         int* __restrict__ cellCursor) {
    const int p = blockIdx.x * blockDim.x + threadIdx.x;
    if (p < N_PTS) {
        const int cx = cell1d(coords[3 * p + 0]);
        const int cy = cell1d(coords[3 * p + 1]);
        const int cz = cell1d(coords[3 * p + 2]);
        atomicAdd(&cellCount[(cz * GRID + cy) * GRID + cx], 1);
    }
    __threadfence();
    __syncthreads();
    __shared__ bool isLast;
    if (threadIdx.x == 0)
        isLast = (atomicAdd(doneCtr, 1) == (int)gridDim.x - 1);
    __syncthreads();
    if (!isLast) return;

    __shared__ int part[256];
    const int t = threadIdx.x;
    const int base = t * 7;                   // 256*7 = 1792 >= 1728
    int local[7];
    int s = 0;
#pragma unroll
    for (int i = 0; i < 7; ++i) {
        const int c = base + i;
        const int v = (c < NCELLS)
            ? __hip_atomic_load(&cellCount[c], __ATOMIC_RELAXED, __HIP_MEMORY_SCOPE_AGENT)
            : 0;
        local[i] = s;
        s += v;
    }
    part[t] = s;
    __syncthreads();
    for (int off = 1; off < 256; off <<= 1) {
        const int v = part[t] + ((t >= off) ? part[t - off] : 0);
        __syncthreads();
        part[t] = v;
        __syncthreads();
    }
    const int excl = (t > 0) ? part[t - 1] : 0;
#pragma unroll
    for (int i = 0; i < 7; ++i) {
        const int c = base + i;
        if (c < NCELLS) {
            cellStart[c] = excl + local[i];
            cellCursor[c] = excl + local[i];
        }
    }
    if (t == 255) cellStart[NCELLS] = part[255];
}

// ---------------------------------------------------------------------------
// Scatter (counting sort) + gather logits row + FUSED softmax -> q0s, ls.
// ---------------------------------------------------------------------------
__global__ __launch_bounds__(256) void scatter_kernel(const float* __restrict__ coords,
                                                      const float* __restrict__ logits,
                                                      int* __restrict__ cellCursor,
                                                      float4* __restrict__ sortedPts,
                                                      int* __restrict__ orig,
                                                      float* __restrict__ ls,
                                                      float* __restrict__ q0s) {
    const int p = blockIdx.x * blockDim.x + threadIdx.x;
    if (p >= N_PTS) return;
    const float x = coords[3 * p + 0];
    const float y = coords[3 * p + 1];
    const float z = coords[3 * p + 2];
    const int c = (cell1d(z) * GRID + cell1d(y)) * GRID + cell1d(x);
    const int pos = atomicAdd(&cellCursor[c], 1);
    sortedPts[pos] = make_float4(x, y, z, __uint_as_float((unsigned)p));
    orig[pos] = p;
    const float4* l4 = (const float4*)(logits + p * NCLS);
    float v[NCLS];
#pragma unroll
    for (int u = 0; u < 5; ++u) {
        const float4 a = l4[u];
        v[4 * u + 0] = a.x; v[4 * u + 1] = a.y;
        v[4 * u + 2] = a.z; v[4 * u + 3] = a.w;
    }
    float4* d4 = (float4*)(ls + pos * NCLS);
#pragma unroll
    for (int u = 0; u < 5; ++u)
        d4[u] = make_float4(v[4 * u], v[4 * u + 1], v[4 * u + 2], v[4 * u + 3]);
    float mx = v[0];
#pragma unroll
    for (int cc = 1; cc < NCLS; ++cc) mx = fmaxf(mx, v[cc]);
    float sum = 0.f;
#pragma unroll
    for (int cc = 0; cc < NCLS; ++cc) { v[cc] = __expf(v[cc] - mx); sum += v[cc]; }
    const float inv = 1.f / sum;
    float4* q4 = (float4*)(q0s + pos * NCLS);
#pragma unroll
    for (int u = 0; u < 5; ++u)
        q4[u] = make_float4(v[4 * u] * inv, v[4 * u + 1] * inv,
                            v[4 * u + 2] * inv, v[4 * u + 3] * inv);
}

// ---------------------------------------------------------------------------
// kNN fast: TWO blocks per cell (3456 blocks, 12KB LDS -> 8 blocks/CU).
// Stage 3^3 candidates once; waves split the cell's points. Filter d2<tau
// (tau <= h^2 => coverage exact on accept), rank-by-broadcast top-16.
// Points needing radius > h (clipped boundary density, ~7%) -> failList.
// NO global-memory ladder here: keeps blocks uniform (no boundary tail).
// ---------------------------------------------------------------------------
__global__ __launch_bounds__(256) void knn_kernel(const float4* __restrict__ sortedPts,
                                                  const int* __restrict__ cellStart,
                                                  int* __restrict__ knn_out,
                                                  int* __restrict__ failList,
                                                  int* __restrict__ failCount) {
    __shared__ float4 cand[CAND_CAP];                 // 8 KB
    __shared__ unsigned long long keys[4][KEY_CAP];   // 4 KB
    const int lane = threadIdx.x & 63;
    const int wave = threadIdx.x >> 6;
    const int c = blockIdx.x >> 1;
    const int half = blockIdx.x & 1;
    const int cz = c / (GRID * GRID);
    const int cy = (c / GRID) % GRID;
    const int cx = c % GRID;
    const int pbeg = cellStart[c];
    const int pend = cellStart[c + 1];
    const int npts = pend - pbeg;
    if (npts <= 0) return;
    const unsigned long long laneLt = (1ull << lane) - 1ull;

    const int xlo = max(cx - 1, 0), xhi = min(cx + 1, GRID - 1);
    const int ylo = max(cy - 1, 0), yhi = min(cy + 1, GRID - 1);
    const int zlo = max(cz - 1, 0), zhi = min(cz + 1, GRID - 1);
    const int ny = yhi - ylo + 1;
    const int nruns = (zhi - zlo + 1) * ny;           // <= 9 x-contiguous runs

    int beg = 0, len = 0;
    if (lane < nruns) {
        const int zz = zlo + lane / ny;
        const int yy = ylo + lane % ny;
        const int rowc = (zz * GRID + yy) * GRID;
        beg = cellStart[rowc + xlo];
        len = cellStart[rowc + xhi + 1] - beg;
    }
    int off = len;
#pragma unroll
    for (int sh = 1; sh < 16; sh <<= 1) {
        const int o = __shfl_up(off, sh, 64);
        if (lane >= sh) off += o;
    }
    const int nc = __shfl(off, nruns - 1);
    off -= len;                                        // exclusive
    const int ownRun = (cz - zlo) * ny + (cy - ylo);
    const int ownOff = __shfl(off, ownRun) + (pbeg - __shfl(beg, ownRun));

    if (nc > CAND_CAP) {                               // ~never (6+ sigma)
        if (threadIdx.x == 0) {
            const int nmine = (npts - half + 1) / 2;   // ceil for half=0
            int b = atomicAdd(failCount, nmine);
            for (int idx = half; idx < npts; idx += 2) failList[b++] = pbeg + idx;
        }
        return;
    }

    for (int r = wave; r < nruns; r += 4) {
        const int rb = __shfl(beg, r);
        const int rl = __shfl(len, r);
        const int ro = __shfl(off, r);
        for (int i = lane; i < rl; i += 64) {
            float4 pt = sortedPts[rb + i];
            pt.w = __uint_as_float((unsigned)(rb + i));
            cand[ro + i] = pt;
        }
    }
    __syncthreads();

    const float taumaxr = 0.9995f * HCELL;
    const float taumax = taumaxr * taumaxr;

    for (int idx = 2 * wave + half; idx < npts; idx += 8) {
        const int s = pbeg + idx;
        const float4 qp = cand[ownOff + idx];
        // boundary-corrected tau targeting E[cnt]~26, capped at coverage h
        float r = R_TARGET;
        const float inv2r = 0.5f / r;
        const float fx = (fminf(qp.x + r, 1.f) - fmaxf(qp.x - r, 0.f)) * inv2r;
        const float fy = (fminf(qp.y + r, 1.f) - fmaxf(qp.y - r, 0.f)) * inv2r;
        const float fz = (fminf(qp.z + r, 1.f) - fmaxf(qp.z - r, 0.f)) * inv2r;
        const float f = fmaxf(fx * fy * fz, 0.05f);
        r = R_TARGET * __powf(f, -0.33333334f);
        float tau = fminf(r * r, taumax);
        bool triedMax = (tau >= taumax * 0.999f);

        int cnt = 0;
        bool ok = false;
        for (int att = 0; att < 5 && !ok; ++att) {
            cnt = 0;
            for (int j0 = 0; j0 < nc; j0 += 64) {
                const int j = j0 + lane;
                float d2 = 1e30f;
                unsigned pw = 0;
                if (j < nc) {
                    const float4 pt = cand[j];
                    const float dx = pt.x - qp.x, dy = pt.y - qp.y, dz = pt.z - qp.z;
                    d2 = dx * dx + dy * dy + dz * dz;
                    pw = __float_as_uint(pt.w);
                }
                const bool take = d2 < tau;
                const unsigned long long mm = __ballot(take);
                if (take) {
                    const int pos = cnt + (int)__popcll(mm & laneLt);
                    if (pos < KEY_CAP)
                        keys[wave][pos] =
                            (((unsigned long long)__float_as_uint(d2)) << 32) |
                            (unsigned long long)pw;
                }
                cnt += (int)__popcll(mm);
            }
            if (cnt >= KNN && cnt <= KEY_CAP) ok = true;
            else if (cnt < KNN) {
                if (triedMax) break;                   // needs radius > h -> slow path
                tau = taumax; triedMax = true;
            } else tau *= 0.6f;
        }
        if (!ok) {
            if (lane == 0) { const int b = atomicAdd(failCount, 1); failList[b] = s; }
            continue;
        }
        const int m = cnt;
        const unsigned long long k0 = (lane < m) ? keys[wave][lane] : ~0ull;
        const unsigned long long k1 = (lane + 64 < m) ? keys[wave][lane + 64] : ~0ull;
        int r0 = 0, r1 = 0;
        for (int j = 0; j < m; ++j) {
            const unsigned long long kj = keys[wave][j];   // LDS broadcast
            r0 += (kj < k0); r1 += (kj < k1);
        }
        if (lane < m && r0 < KNN)      knn_out[s * KNN + r0] = (int)(unsigned)(k0 & 0xffffffffull);
        if (lane + 64 < m && r1 < KNN) knn_out[s * KNN + r1] = (int)(unsigned)(k1 & 0xffffffffull);
    }
}

// ---------------------------------------------------------------------------
// kNN slow: 1 wave per fail point (grid-stride), global-memory ladder hw=2+.
// ~1400 points over 2048 waves -> ~1 point/wave, fully parallel.
// ---------------------------------------------------------------------------
__global__ __launch_bounds__(256) void knn_slow_kernel(const float4* __restrict__ sortedPts,
                                                       const int* __restrict__ cellStart,
                                                       const int* __restrict__ failList,
                                                       const int* __restrict__ failCount,
                                                       int* __restrict__ knn_out) {
    __shared__ unsigned long long keys[4][KEY_CAP];
    const int lane = threadIdx.x & 63;
    const int wave = threadIdx.x >> 6;
    const int wid = blockIdx.x * 4 + wave;
    const int nw = gridDim.x * 4;
    const int nf = failCount[0];
    const unsigned long long laneLt = (1ull << lane) - 1ull;

    for (int fi = wid; fi < nf; fi += nw) {
        const int s = failList[fi];
        const float4 qp = sortedPts[s];
        const int cx = cell1d(qp.x), cy = cell1d(qp.y), cz = cell1d(qp.z);
        int hw = 2;
        float g = 0.9995f * 2.f * HCELL;
        float tau = g * g;
        int cnt = 0;
        for (int att = 0; att < 16; ++att) {
            cnt = 0;
            const int xlo = max(cx - hw, 0), xhi = min(cx + hw, GRID - 1);
            const int ylo = max(cy - hw, 0), yhi = min(cy + hw, GRID - 1);
            const int zlo = max(cz - hw, 0), zhi = min(cz + hw, GRID - 1);
            for (int zz = zlo; zz <= zhi; ++zz) {
                for (int yy = ylo; yy <= yhi; ++yy) {
                    const int rowc = (zz * GRID + yy) * GRID;
                    const int beg = cellStart[rowc + xlo];
                    const int end = cellStart[rowc + xhi + 1];
                    for (int j0 = beg; j0 < end; j0 += 64) {
                        const int j = j0 + lane;
                        const bool jv = j < end;
                        const float4 pt = sortedPts[jv ? j : beg];
                        const float dx = pt.x - qp.x, dy = pt.y - qp.y, dz = pt.z - qp.z;
                        const float d2 = dx * dx + dy * dy + dz * dz;
                        const bool take = jv && (d2 < tau);
                        const unsigned long long mm = __ballot(take);
                        if (take) {
                            const int pos = cnt + (int)__popcll(mm & laneLt);
                            if (pos < KEY_CAP)
                                keys[wave][pos] =
                                    (((unsigned long long)__float_as_uint(d2)) << 32) |
                                    (unsigned long long)(unsigned)j;
                        }
                        cnt += (int)__popcll(mm);
                    }
                }
            }
            if (cnt >= KNN && cnt <= KEY_CAP) break;
            if (cnt < KNN) {
                if (hw < GRID - 1) { ++hw; g = 0.9995f * (float)hw * HCELL; tau = g * g; }
                else tau *= 2.5f;
            } else {
                tau *= 0.6f;
            }
        }
        const int m = min(cnt, KEY_CAP);
        const unsigned long long k0 = (lane < m) ? keys[wave][lane] : ~0ull;
        const unsigned long long k1 = (lane + 64 < m) ? keys[wave][lane + 64] : ~0ull;
        int r0 = 0, r1 = 0;
        for (int j = 0; j < m; ++j) {
            const unsigned long long kj = keys[wave][j];
            r0 += (kj < k0); r1 += (kj < k1);
        }
        if (lane < m && r0 < KNN)      knn_out[s * KNN + r0] = (int)(unsigned)(k0 & 0xffffffffull);
        if (lane + 64 < m && r1 < KNN) knn_out[s * KNN + r1] = (int)(unsigned)(k1 & 0xffffffffull);
    }
}

// ---------------------------------------------------------------------------
// CRF iteration, SORTED space, 4 lanes/point.
// ---------------------------------------------------------------------------
__global__ __launch_bounds__(256) void crf_iter_kernel(const float* __restrict__ ls,
                                                       const float* __restrict__ W,
                                                       const int* __restrict__ knn,
                                                       const float* __restrict__ qin,
                                                       float* __restrict__ qout,
                                                       const int* __restrict__ orig,
                                                       float* __restrict__ outRef,
                                                       float* __restrict__ outQ) {
    __shared__ float Ws[NCLS * NCLS];
    for (int i = threadIdx.x; i < NCLS * NCLS; i += blockDim.x) Ws[i] = W[i];
    __syncthreads();
    const int t = blockIdx.x * blockDim.x + threadIdx.x;
    const int p = t >> 2;
    const int qtr = t & 3;
    if (p >= N_PTS) return;

    float acc[NCLS];
#pragma unroll
    for (int c = 0; c < NCLS; ++c) acc[c] = 0.f;

    const int4 k4 = ((const int4*)(knn + p * KNN))[qtr];
    const int ids[4] = {k4.x, k4.y, k4.z, k4.w};
#pragma unroll
    for (int u = 0; u < 4; ++u) {
        unsigned id = (unsigned)ids[u];
        if (id >= N_PTS) id = 0;        // safety clamp (unreachable)
        const float4* r4 = (const float4*)(qin + id * NCLS);
#pragma unroll
        for (int v = 0; v < 5; ++v) {
            const float4 a = r4[v];
            acc[4 * v + 0] += a.x; acc[4 * v + 1] += a.y;
            acc[4 * v + 2] += a.z; acc[4 * v + 3] += a.w;
        }
    }
#pragma unroll
    for (int c = 0; c < NCLS; ++c) {
        acc[c] += __shfl_xor(acc[c], 1, 64);
        acc[c] += __shfl_xor(acc[c], 2, 64);
        acc[c] *= (1.f / 16.f);          // msg
    }

    const int c0 = qtr * 5;
    float ref[5];
#pragma unroll
    for (int i = 0; i < 5; ++i) {
        float s = ls[p * NCLS + c0 + i];
#pragma unroll
        for (int k = 0; k < NCLS; ++k) s += acc[k] * Ws[(c0 + i) * NCLS + k];  // x@W^T
        ref[i] = s;
    }

    float mx = ref[0];
#pragma unroll
    for (int i = 1; i < 5; ++i) mx = fmaxf(mx, ref[i]);
    mx = fmaxf(mx, __shfl_xor(mx, 1, 64));
    mx = fmaxf(mx, __shfl_xor(mx, 2, 64));
    float ex[5];
    float ps = 0.f;
#pragma unroll
    for (int i = 0; i < 5; ++i) { ex[i] = __expf(ref[i] - mx); ps += ex[i]; }
    ps += __shfl_xor(ps, 1, 64);
    ps += __shfl_xor(ps, 2, 64);
    const float inv = 1.f / ps;

    if (outRef != nullptr) {
        const int o = orig[p];
#pragma unroll
        for (int i = 0; i < 5; ++i) {
            outRef[o * NCLS + c0 + i] = ref[i];
            outQ[o * NCLS + c0 + i] = ex[i] * inv;
        }
    } else {
#pragma unroll
        for (int i = 0; i < 5; ++i) qout[p * NCLS + c0 + i] = ex[i] * inv;
    }
}

// ---------------------------------------------------------------------------
extern "C" void kernel_launch(void* const* d_in, const int* in_sizes, int n_in,
                              void* d_out, int out_size, void* d_ws, size_t ws_size,
                              hipStream_t stream) {
    const float* logits = (const float*)d_in[0];   // (20000, 20)
    const float* coords = (const float*)d_in[1];   // (20000, 3)
    const float* W      = (const float*)d_in[2];   // (20, 20)
    float* out = (float*)d_out;                    // refined (400000) | q (400000)

    // workspace (~5 MB); q1s aliases out's q-region (safe: final pass reads
    // only q0s/ls/knn/orig and overwrites that region last).
    char* ws = (char*)d_ws;
    size_t off = 0;
    int* knn = (int*)(ws + off);              off += (size_t)N_PTS * KNN * 4;
    off = (off + 255) & ~(size_t)255;
    float* ls = (float*)(ws + off);           off += (size_t)N_PTS * NCLS * 4;
    off = (off + 255) & ~(size_t)255;
    float* q0s = (float*)(ws + off);          off += (size_t)N_PTS * NCLS * 4;
    off = (off + 255) & ~(size_t)255;
    float4* sortedPts = (float4*)(ws + off);  off += (size_t)N_PTS * 16;
    off = (off + 255) & ~(size_t)255;
    int* orig = (int*)(ws + off);             off += (size_t)N_PTS * 4;
    off = (off + 255) & ~(size_t)255;
    int* failList = (int*)(ws + off);         off += (size_t)N_PTS * 4;
    off = (off + 255) & ~(size_t)255;
    int* cellCount = (int*)(ws + off);        off += (size_t)(NCELLS + 2) * 4;
    int* doneCtr = cellCount + NCELLS;        // zeroed with cellCount
    int* failCount = cellCount + NCELLS + 1;  // zeroed with cellCount
    off = (off + 255) & ~(size_t)255;
    int* cellStart = (int*)(ws + off);        off += (size_t)(NCELLS + 1) * 4;
    off = (off + 255) & ~(size_t)255;
    int* cellCursor = (int*)(ws + off);
    float* q1s = out + N_PTS * NCLS;

    const int threads = 256;
    const int pblocks = (N_PTS + threads - 1) / threads;
    const int cblocks = (4 * N_PTS + threads - 1) / threads;

    hipMemsetAsync(cellCount, 0, (NCELLS + 2) * sizeof(int), stream);
    count_scan_kernel<<<pblocks, threads, 0, stream>>>(coords, cellCount, doneCtr,
                                                       cellStart, cellCursor);
    scatter_kernel<<<pblocks, threads, 0, stream>>>(coords, logits, cellCursor,
                                                    sortedPts, orig, ls, q0s);
    knn_kernel<<<NCELLS * 2, threads, 0, stream>>>(sortedPts, cellStart, knn,
                                                   failList, failCount);
    knn_slow_kernel<<<512, threads, 0, stream>>>(sortedPts, cellStart, failList,
                                                 failCount, knn);
    crf_iter_kernel<<<cblocks, threads, 0, stream>>>(ls, W, knn, q0s, q1s, orig,
                                                     nullptr, nullptr);
    crf_iter_kernel<<<cblocks, threads, 0, stream>>>(ls, W, knn, q1s, q0s, orig,
                                                     nullptr, nullptr);
    crf_iter_kernel<<<cblocks, threads, 0, stream>>>(ls, W, knn, q0s, nullptr, orig,
                                                     out, out + N_PTS * NCLS);
}

// Round 7
// 128.511 us; speedup vs baseline: 1.1492x; 1.1492x over previous
//
#include <hip/hip_runtime.h>

#define N_PTS 20000
#define NCLS 20
#define KNN 16
#define GRID 12
#define NCELLS (GRID * GRID * GRID)
#define HCELL (1.0f / (float)GRID)
#define CAND_CAP 640       // worst staged block: bd>=2 hs=2 clipped 5^3 E~521 +5sig
#define KEY_CAP 128        // filtered keys per point (E~26; taumax corner E~48, edge E~96)
#define R_TARGET 0.0680f   // radius giving E[cnt]~26 in the interior

__device__ __forceinline__ int cell1d(float v) {
    int c = (int)(v * (float)GRID);
    return min(max(c, 0), GRID - 1);
}

// ---------------------------------------------------------------------------
// Count (grid-wide atomics) + fused scan: last block performs the 1728-cell
// exclusive scan (agent-scope loads; done-counter handshake).
// ---------------------------------------------------------------------------
__global__ __launch_bounds__(256) void count_scan_kernel(const float* __restrict__ coords,
                                                         int* __restrict__ cellCount,
                                                         int* __restrict__ doneCtr,
                                                         int* __restrict__ cellStart,
                                                         int* __restrict__ cellCursor) {
    const int p = blockIdx.x * blockDim.x + threadIdx.x;
    if (p < N_PTS) {
        const int cx = cell1d(coords[3 * p + 0]);
        const int cy = cell1d(coords[3 * p + 1]);
        const int cz = cell1d(coords[3 * p + 2]);
        atomicAdd(&cellCount[(cz * GRID + cy) * GRID + cx], 1);
    }
    __threadfence();
    __syncthreads();
    __shared__ bool isLast;
    if (threadIdx.x == 0)
        isLast = (atomicAdd(doneCtr, 1) == (int)gridDim.x - 1);
    __syncthreads();
    if (!isLast) return;

    __shared__ int part[256];
    const int t = threadIdx.x;
    const int base = t * 7;                   // 256*7 = 1792 >= 1728
    int local[7];
    int s = 0;
#pragma unroll
    for (int i = 0; i < 7; ++i) {
        const int c = base + i;
        const int v = (c < NCELLS)
            ? __hip_atomic_load(&cellCount[c], __ATOMIC_RELAXED, __HIP_MEMORY_SCOPE_AGENT)
            : 0;
        local[i] = s;
        s += v;
    }
    part[t] = s;
    __syncthreads();
    for (int off = 1; off < 256; off <<= 1) {
        const int v = part[t] + ((t >= off) ? part[t - off] : 0);
        __syncthreads();
        part[t] = v;
        __syncthreads();
    }
    const int excl = (t > 0) ? part[t - 1] : 0;
#pragma unroll
    for (int i = 0; i < 7; ++i) {
        const int c = base + i;
        if (c < NCELLS) {
            cellStart[c] = excl + local[i];
            cellCursor[c] = excl + local[i];
        }
    }
    if (t == 255) cellStart[NCELLS] = part[255];
}

// ---------------------------------------------------------------------------
// Scatter (counting sort) + gather logits row + FUSED softmax -> q0s, ls.
// ---------------------------------------------------------------------------
__global__ __launch_bounds__(256) void scatter_kernel(const float* __restrict__ coords,
                                                      const float* __restrict__ logits,
                                                      int* __restrict__ cellCursor,
                                                      float4* __restrict__ sortedPts,
                                                      int* __restrict__ orig,
                                                      float* __restrict__ ls,
                                                      float* __restrict__ q0s) {
    const int p = blockIdx.x * blockDim.x + threadIdx.x;
    if (p >= N_PTS) return;
    const float x = coords[3 * p + 0];
    const float y = coords[3 * p + 1];
    const float z = coords[3 * p + 2];
    const int c = (cell1d(z) * GRID + cell1d(y)) * GRID + cell1d(x);
    const int pos = atomicAdd(&cellCursor[c], 1);
    sortedPts[pos] = make_float4(x, y, z, __uint_as_float((unsigned)p));
    orig[pos] = p;
    const float4* l4 = (const float4*)(logits + p * NCLS);
    float v[NCLS];
#pragma unroll
    for (int u = 0; u < 5; ++u) {
        const float4 a = l4[u];
        v[4 * u + 0] = a.x; v[4 * u + 1] = a.y;
        v[4 * u + 2] = a.z; v[4 * u + 3] = a.w;
    }
    float4* d4 = (float4*)(ls + pos * NCLS);
#pragma unroll
    for (int u = 0; u < 5; ++u)
        d4[u] = make_float4(v[4 * u], v[4 * u + 1], v[4 * u + 2], v[4 * u + 3]);
    float mx = v[0];
#pragma unroll
    for (int cc = 1; cc < NCLS; ++cc) mx = fmaxf(mx, v[cc]);
    float sum = 0.f;
#pragma unroll
    for (int cc = 0; cc < NCLS; ++cc) { v[cc] = __expf(v[cc] - mx); sum += v[cc]; }
    const float inv = 1.f / sum;
    float4* q4 = (float4*)(q0s + pos * NCLS);
#pragma unroll
    for (int u = 0; u < 5; ++u)
        q4[u] = make_float4(v[4 * u] * inv, v[4 * u + 1] * inv,
                            v[4 * u + 2] * inv, v[4 * u + 3] * inv);
}

// ---------------------------------------------------------------------------
// Rare exact fallback: wave-cooperative global-memory ladder (hw growing).
// Only ~100-200 face-cell points (Poisson undercount) ever reach this.
// ---------------------------------------------------------------------------
__device__ void knn_ladder(const float4* __restrict__ sortedPts,
                           const int* __restrict__ cellStart,
                           const float4 qp, const int s, int hw,
                           unsigned long long* keys, const int lane,
                           int* __restrict__ knn_out) {
    const unsigned long long laneLt = (1ull << lane) - 1ull;
    const int cx = cell1d(qp.x), cy = cell1d(qp.y), cz = cell1d(qp.z);
    float g = 0.9995f * (float)hw * HCELL;
    float tau = g * g;
    int cnt = 0;
    for (int att = 0; att < 16; ++att) {
        cnt = 0;
        const int xlo = max(cx - hw, 0), xhi = min(cx + hw, GRID - 1);
        const int ylo = max(cy - hw, 0), yhi = min(cy + hw, GRID - 1);
        const int zlo = max(cz - hw, 0), zhi = min(cz + hw, GRID - 1);
        for (int zz = zlo; zz <= zhi; ++zz) {
            for (int yy = ylo; yy <= yhi; ++yy) {
                const int rowc = (zz * GRID + yy) * GRID;
                const int beg = cellStart[rowc + xlo];
                const int end = cellStart[rowc + xhi + 1];
                for (int j0 = beg; j0 < end; j0 += 64) {
                    const int j = j0 + lane;
                    const bool jv = j < end;
                    const float4 pt = sortedPts[jv ? j : beg];
                    const float dx = pt.x - qp.x, dy = pt.y - qp.y, dz = pt.z - qp.z;
                    const float d2 = dx * dx + dy * dy + dz * dz;
                    const bool take = jv && (d2 < tau);
                    const unsigned long long mm = __ballot(take);
                    if (take) {
                        const int pos = cnt + (int)__popcll(mm & laneLt);
                        if (pos < KEY_CAP)
                            keys[pos] = (((unsigned long long)__float_as_uint(d2)) << 32) |
                                        (unsigned long long)(unsigned)j;
                    }
                    cnt += (int)__popcll(mm);
                }
            }
        }
        if (cnt >= KNN && cnt <= KEY_CAP) break;
        if (cnt < KNN) {
            if (hw < GRID - 1) { ++hw; g = 0.9995f * (float)hw * HCELL; tau = g * g; }
            else tau *= 2.5f;
        } else {
            tau *= 0.6f;
        }
    }
    const int m = min(cnt, KEY_CAP);
    const unsigned long long k0 = (lane < m) ? keys[lane] : ~0ull;
    const unsigned long long k1 = (lane + 64 < m) ? keys[lane + 64] : ~0ull;
    int r0 = 0, r1 = 0;
    for (int j = 0; j < m; ++j) {
        const unsigned long long kj = keys[j];
        r0 += (kj < k0); r1 += (kj < k1);
    }
    if (lane < m && r0 < KNN)      knn_out[s * KNN + r0] = (int)(unsigned)(k0 & 0xffffffffull);
    if (lane + 64 < m && r1 < KNN) knn_out[s * KNN + r1] = (int)(unsigned)(k1 & 0xffffffffull);
}

// ---------------------------------------------------------------------------
// kNN: TWO blocks per cell (3456 blocks, 14.3KB LDS -> 8 blocks/CU).
// Interior/face cells stage the 3^3 region (coverage h); edge/corner cells
// (bd>=2) stage the clipped 5^3 region (coverage 2h >= corner r16) so they
// resolve in the fast path too. Since no points exist outside [0,1]^3, the
// staged region is EXACT for radius <= hs*h. Filter d2<tau (tau <= coverage^2
// => exact on accept), rank-by-broadcast top-16. Rare undercounts (Poisson
// tail in face cells) use the inline global ladder.
// ---------------------------------------------------------------------------
__global__ __launch_bounds__(256) void knn_kernel(const float4* __restrict__ sortedPts,
                                                  const int* __restrict__ cellStart,
                                                  int* __restrict__ knn_out) {
    __shared__ float4 cand[CAND_CAP];                 // 10.24 KB
    __shared__ unsigned long long keys[4][KEY_CAP];   // 4 KB
    const int lane = threadIdx.x & 63;
    const int wave = threadIdx.x >> 6;
    const int c = blockIdx.x >> 1;
    const int half = blockIdx.x & 1;
    const int cz = c / (GRID * GRID);
    const int cy = (c / GRID) % GRID;
    const int cx = c % GRID;
    const int pbeg = cellStart[c];
    const int pend = cellStart[c + 1];
    const int npts = pend - pbeg;
    if (npts <= 0) return;
    const int bd = (cx == 0 || cx == GRID - 1) + (cy == 0 || cy == GRID - 1) +
                   (cz == 0 || cz == GRID - 1);
    const int hs = (bd >= 2) ? 2 : 1;                 // staging halo width
    const unsigned long long laneLt = (1ull << lane) - 1ull;

    const int xlo = max(cx - hs, 0), xhi = min(cx + hs, GRID - 1);
    const int ylo = max(cy - hs, 0), yhi = min(cy + hs, GRID - 1);
    const int zlo = max(cz - hs, 0), zhi = min(cz + hs, GRID - 1);
    const int ny = yhi - ylo + 1;
    const int nruns = (zhi - zlo + 1) * ny;           // <= 25 x-contiguous runs

    int beg = 0, len = 0;
    if (lane < nruns) {
        const int zz = zlo + lane / ny;
        const int yy = ylo + lane % ny;
        const int rowc = (zz * GRID + yy) * GRID;
        beg = cellStart[rowc + xlo];
        len = cellStart[rowc + xhi + 1] - beg;
    }
    int off = len;
#pragma unroll
    for (int sh = 1; sh < 32; sh <<= 1) {
        const int o = __shfl_up(off, sh, 64);
        if (lane >= sh) off += o;
    }
    const int nc = __shfl(off, nruns - 1);
    off -= len;                                        // exclusive
    const int ownRun = (cz - zlo) * ny + (cy - ylo);
    const int ownOff = __shfl(off, ownRun) + (pbeg - __shfl(beg, ownRun));

    if (nc <= CAND_CAP) {
        for (int r = wave; r < nruns; r += 4) {
            const int rb = __shfl(beg, r);
            const int rl = __shfl(len, r);
            const int ro = __shfl(off, r);
            for (int i = lane; i < rl; i += 64) {
                float4 pt = sortedPts[rb + i];
                pt.w = __uint_as_float((unsigned)(rb + i));
                cand[ro + i] = pt;
            }
        }
    }
    __syncthreads();

    if (nc > CAND_CAP) {                               // ~never (>5 sigma)
        for (int idx = 2 * wave + half; idx < npts; idx += 8)
            knn_ladder(sortedPts, cellStart, sortedPts[pbeg + idx], pbeg + idx,
                       hs, keys[wave], lane, knn_out);
        return;
    }

    const float taumaxr = 0.9995f * (float)hs * HCELL;
    const float taumax = taumaxr * taumaxr;

    for (int idx = 2 * wave + half; idx < npts; idx += 8) {
        const int s = pbeg + idx;
        const float4 qp = cand[ownOff + idx];
        // boundary-corrected tau targeting E[cnt]~26, capped at coverage hs*h
        float r = R_TARGET;
        const float inv2r = 0.5f / r;
        const float fx = (fminf(qp.x + r, 1.f) - fmaxf(qp.x - r, 0.f)) * inv2r;
        const float fy = (fminf(qp.y + r, 1.f) - fmaxf(qp.y - r, 0.f)) * inv2r;
        const float fz = (fminf(qp.z + r, 1.f) - fmaxf(qp.z - r, 0.f)) * inv2r;
        const float f = fmaxf(fx * fy * fz, 0.05f);
        r = R_TARGET * __powf(f, -0.33333334f);
        float tau = fminf(r * r, taumax);
        bool triedMax = (tau >= taumax * 0.999f);

        int cnt = 0;
        bool ok = false;
        for (int att = 0; att < 5 && !ok; ++att) {
            cnt = 0;
            for (int j0 = 0; j0 < nc; j0 += 64) {
                const int j = j0 + lane;
                float d2 = 1e30f;
                unsigned pw = 0;
                if (j < nc) {
                    const float4 pt = cand[j];
                    const float dx = pt.x - qp.x, dy = pt.y - qp.y, dz = pt.z - qp.z;
                    d2 = dx * dx + dy * dy + dz * dz;
                    pw = __float_as_uint(pt.w);
                }
                const bool take = d2 < tau;
                const unsigned long long mm = __ballot(take);
                if (take) {
                    const int pos = cnt + (int)__popcll(mm & laneLt);
                    if (pos < KEY_CAP)
                        keys[wave][pos] =
                            (((unsigned long long)__float_as_uint(d2)) << 32) |
                            (unsigned long long)pw;
                }
                cnt += (int)__popcll(mm);
            }
            if (cnt >= KNN && cnt <= KEY_CAP) ok = true;
            else if (cnt < KNN) {
                if (triedMax) break;                   // needs radius > hs*h -> ladder
                tau = taumax; triedMax = true;
            } else tau *= 0.6f;
        }
        if (!ok) {                                     // rare Poisson-tail points
            knn_ladder(sortedPts, cellStart, qp, s, hs + 1, keys[wave], lane, knn_out);
            continue;
        }
        const int m = cnt;
        const unsigned long long k0 = (lane < m) ? keys[wave][lane] : ~0ull;
        const unsigned long long k1 = (lane + 64 < m) ? keys[wave][lane + 64] : ~0ull;
        int r0 = 0, r1 = 0;
        for (int j = 0; j < m; ++j) {
            const unsigned long long kj = keys[wave][j];   // LDS broadcast
            r0 += (kj < k0); r1 += (kj < k1);
        }
        if (lane < m && r0 < KNN)      knn_out[s * KNN + r0] = (int)(unsigned)(k0 & 0xffffffffull);
        if (lane + 64 < m && r1 < KNN) knn_out[s * KNN + r1] = (int)(unsigned)(k1 & 0xffffffffull);
    }
}

// ---------------------------------------------------------------------------
// CRF iteration, SORTED space, 4 lanes/point.
// ---------------------------------------------------------------------------
__global__ __launch_bounds__(256) void crf_iter_kernel(const float* __restrict__ ls,
                                                       const float* __restrict__ W,
                                                       const int* __restrict__ knn,
                                                       const float* __restrict__ qin,
                                                       float* __restrict__ qout,
                                                       const int* __restrict__ orig,
                                                       float* __restrict__ outRef,
                                                       float* __restrict__ outQ) {
    __shared__ float Ws[NCLS * NCLS];
    for (int i = threadIdx.x; i < NCLS * NCLS; i += blockDim.x) Ws[i] = W[i];
    __syncthreads();
    const int t = blockIdx.x * blockDim.x + threadIdx.x;
    const int p = t >> 2;
    const int qtr = t & 3;
    if (p >= N_PTS) return;

    float acc[NCLS];
#pragma unroll
    for (int c = 0; c < NCLS; ++c) acc[c] = 0.f;

    const int4 k4 = ((const int4*)(knn + p * KNN))[qtr];
    const int ids[4] = {k4.x, k4.y, k4.z, k4.w};
#pragma unroll
    for (int u = 0; u < 4; ++u) {
        unsigned id = (unsigned)ids[u];
        if (id >= N_PTS) id = 0;        // safety clamp (unreachable)
        const float4* r4 = (const float4*)(qin + id * NCLS);
#pragma unroll
        for (int v = 0; v < 5; ++v) {
            const float4 a = r4[v];
            acc[4 * v + 0] += a.x; acc[4 * v + 1] += a.y;
            acc[4 * v + 2] += a.z; acc[4 * v + 3] += a.w;
        }
    }
#pragma unroll
    for (int c = 0; c < NCLS; ++c) {
        acc[c] += __shfl_xor(acc[c], 1, 64);
        acc[c] += __shfl_xor(acc[c], 2, 64);
        acc[c] *= (1.f / 16.f);          // msg
    }

    const int c0 = qtr * 5;
    float ref[5];
#pragma unroll
    for (int i = 0; i < 5; ++i) {
        float s = ls[p * NCLS + c0 + i];
#pragma unroll
        for (int k = 0; k < NCLS; ++k) s += acc[k] * Ws[(c0 + i) * NCLS + k];  // x@W^T
        ref[i] = s;
    }

    float mx = ref[0];
#pragma unroll
    for (int i = 1; i < 5; ++i) mx = fmaxf(mx, ref[i]);
    mx = fmaxf(mx, __shfl_xor(mx, 1, 64));
    mx = fmaxf(mx, __shfl_xor(mx, 2, 64));
    float ex[5];
    float ps = 0.f;
#pragma unroll
    for (int i = 0; i < 5; ++i) { ex[i] = __expf(ref[i] - mx); ps += ex[i]; }
    ps += __shfl_xor(ps, 1, 64);
    ps += __shfl_xor(ps, 2, 64);
    const float inv = 1.f / ps;

    if (outRef != nullptr) {
        const int o = orig[p];
#pragma unroll
        for (int i = 0; i < 5; ++i) {
            outRef[o * NCLS + c0 + i] = ref[i];
            outQ[o * NCLS + c0 + i] = ex[i] * inv;
        }
    } else {
#pragma unroll
        for (int i = 0; i < 5; ++i) qout[p * NCLS + c0 + i] = ex[i] * inv;
    }
}

// ---------------------------------------------------------------------------
extern "C" void kernel_launch(void* const* d_in, const int* in_sizes, int n_in,
                              void* d_out, int out_size, void* d_ws, size_t ws_size,
                              hipStream_t stream) {
    const float* logits = (const float*)d_in[0];   // (20000, 20)
    const float* coords = (const float*)d_in[1];   // (20000, 3)
    const float* W      = (const float*)d_in[2];   // (20, 20)
    float* out = (float*)d_out;                    // refined (400000) | q (400000)

    // workspace (~5 MB); q1s aliases out's q-region (safe: final pass reads
    // only q0s/ls/knn/orig and overwrites that region last).
    char* ws = (char*)d_ws;
    size_t off = 0;
    int* knn = (int*)(ws + off);              off += (size_t)N_PTS * KNN * 4;
    off = (off + 255) & ~(size_t)255;
    float* ls = (float*)(ws + off);           off += (size_t)N_PTS * NCLS * 4;
    off = (off + 255) & ~(size_t)255;
    float* q0s = (float*)(ws + off);          off += (size_t)N_PTS * NCLS * 4;
    off = (off + 255) & ~(size_t)255;
    float4* sortedPts = (float4*)(ws + off);  off += (size_t)N_PTS * 16;
    off = (off + 255) & ~(size_t)255;
    int* orig = (int*)(ws + off);             off += (size_t)N_PTS * 4;
    off = (off + 255) & ~(size_t)255;
    int* cellCount = (int*)(ws + off);        off += (size_t)(NCELLS + 1) * 4;
    int* doneCtr = cellCount + NCELLS;        // zeroed with cellCount
    off = (off + 255) & ~(size_t)255;
    int* cellStart = (int*)(ws + off);        off += (size_t)(NCELLS + 1) * 4;
    off = (off + 255) & ~(size_t)255;
    int* cellCursor = (int*)(ws + off);
    float* q1s = out + N_PTS * NCLS;

    const int threads = 256;
    const int pblocks = (N_PTS + threads - 1) / threads;
    const int cblocks = (4 * N_PTS + threads - 1) / threads;

    hipMemsetAsync(cellCount, 0, (NCELLS + 1) * sizeof(int), stream);
    count_scan_kernel<<<pblocks, threads, 0, stream>>>(coords, cellCount, doneCtr,
                                                       cellStart, cellCursor);
    scatter_kernel<<<pblocks, threads, 0, stream>>>(coords, logits, cellCursor,
                                                    sortedPts, orig, ls, q0s);
    knn_kernel<<<NCELLS * 2, threads, 0, stream>>>(sortedPts, cellStart, knn);
    crf_iter_kernel<<<cblocks, threads, 0, stream>>>(ls, W, knn, q0s, q1s, orig,
                                                     nullptr, nullptr);
    crf_iter_kernel<<<cblocks, threads, 0, stream>>>(ls, W, knn, q1s, q0s, orig,
                                                     nullptr, nullptr);
    crf_iter_kernel<<<cblocks, threads, 0, stream>>>(ls, W, knn, q0s, nullptr, orig,
                                                     out, out + N_PTS * NCLS);
}